// Round 10
// baseline (3064.696 us; speedup 1.0000x reference)
//
#include <hip/hip_runtime.h>
#include <hip/hip_bf16.h>
#include <stdint.h>
#include <math.h>

#define NBATCH 512
#define NS 256
#define NE 128
#define NH 128
#define NSTEPS 255
#define NEGINF -1e8f
#define SENT_NEG -1e30f

// ---------------- threefry2x32 (partitionable path, verified r2..r9) ----------------
__device__ __forceinline__ uint32_t rotl32(uint32_t x, uint32_t r) {
  return (x << r) | (x >> (32u - r));
}

__device__ __forceinline__ void tf2x32(uint32_t k0, uint32_t k1,
                                       uint32_t x0, uint32_t x1,
                                       uint32_t& o0, uint32_t& o1) {
  uint32_t ks2 = k0 ^ k1 ^ 0x1BD11BDAu;
  x0 += k0; x1 += k1;
#define TF_R4(a,b,c,d) \
  x0 += x1; x1 = rotl32(x1,a); x1 ^= x0; \
  x0 += x1; x1 = rotl32(x1,b); x1 ^= x0; \
  x0 += x1; x1 = rotl32(x1,c); x1 ^= x0; \
  x0 += x1; x1 = rotl32(x1,d); x1 ^= x0;
  TF_R4(13,15,26,6)   x0 += k1;  x1 += ks2 + 1u;
  TF_R4(17,29,16,24)  x0 += ks2; x1 += k0 + 2u;
  TF_R4(13,15,26,6)   x0 += k0;  x1 += k1 + 3u;
  TF_R4(17,29,16,24)  x0 += k1;  x1 += ks2 + 4u;
  TF_R4(13,15,26,6)   x0 += ks2; x1 += k0 + 5u;
#undef TF_R4
  o0 = x0; o1 = x1;
}

__device__ __forceinline__ float gumbel_of(uint2 key, uint32_t j) {
  uint32_t o0, o1;
  tf2x32(key.x, key.y, 0u, j, o0, o1);
  uint32_t bits = o0 ^ o1;
  float f = __uint_as_float((bits >> 9) | 0x3f800000u) - 1.0f;
  float u = (f == 0.0f) ? 1.17549435e-38f : f;
  float l1 = -logf(u);
  return -logf(l1);
}

// tanh via hw exp2 + rcp + 1 Newton step (verified exact-index r3..r9)
__device__ __forceinline__ float nr_tanh(float x) {
  const float Chi = 2.8853900432586670f;
  const float Clo = 3.8519259822379735e-08f;
  float m = fmaf(x, Chi, x * Clo);
  m = fminf(m, 126.0f);
  float tt = __builtin_amdgcn_exp2f(m);
  float d  = tt + 1.0f;
  float r  = __builtin_amdgcn_rcpf(d);
  r = r * fmaf(-d, r, 2.0f);
  return fmaf(-2.0f, r, 1.0f);
}

__device__ __forceinline__ double dot32(const float4* __restrict__ a,
                                        const float4* __restrict__ bp) {
  double s = 0.0;
#pragma unroll
  for (int q = 0; q < 8; ++q) {
    float4 x = a[q], y = bp[q];
    s += (double)x.x * (double)y.x + (double)x.y * (double)y.y
       + (double)x.z * (double)y.z + (double)x.w * (double)y.w;
  }
  return s;
}

__device__ __forceinline__ double dot4d(float4 a, float4 b) {
  return ((double)a.x * (double)b.x + (double)a.y * (double)b.y)
       + ((double)a.z * (double)b.z + (double)a.w * (double)b.w);
}

// ======================= precompute kernels (unchanged from r8) =======================
__global__ void k1_mats(const float* __restrict__ Wv, const float* __restrict__ Wq,
                        const float* __restrict__ liw, const float* __restrict__ bvv,
                        float* __restrict__ M1T, float* __restrict__ M2T,
                        float* __restrict__ rest0) {
  int e = blockIdx.x, h = threadIdx.x;
  __shared__ float wrow[NE];
  if (e < 256) {
    wrow[h] = Wv[e * NE + h];
    __syncthreads();
    double a = 0.0;
    for (int k = 0; k < NE; ++k) a += (double)wrow[k] * (double)Wq[k * NH + h];
    if (e < 128) M1T[h * NE + e] = (float)a;
    else         M2T[h * NE + (e - 128)] = (float)a;
  } else {
    double a = 0.0;
    for (int k = 0; k < 2 * NE; ++k) a += (double)liw[k] * (double)Wv[k * NE + h];
    rest0[h] = (float)a + bvv[h];
  }
}

__global__ void k2_base(const float* __restrict__ cv, const float* __restrict__ Wc,
                        const float* __restrict__ bc, const float* __restrict__ bvv,
                        const float* __restrict__ Wq, const float* __restrict__ rest0,
                        double* __restrict__ qqbase, float* __restrict__ qq0) {
  int b = blockIdx.x, h = threadIdx.x;
  int b256 = b << 8;
  __shared__ float meanL[NE], hbarL[NE];
  double ms = 0.0;
  for (int s = 0; s < NS; ++s) ms += (double)cv[((size_t)b256 + s) * NE + h];
  meanL[h] = (float)(ms * (1.0 / 256.0));
  __syncthreads();
  double a = 0.0;
  for (int e = 0; e < NE; ++e) a += (double)meanL[e] * (double)Wc[e * NE + h];
  hbarL[h] = (float)a + bc[h];
  __syncthreads();
  double ab = 0.0, a0 = 0.0;
  for (int k = 0; k < NE; ++k) {
    double w = (double)Wq[k * NH + h];
    ab += (double)(hbarL[k] + bvv[k]) * w;
    a0 += (double)(hbarL[k] + rest0[k]) * w;
  }
  qqbase[(size_t)b * NH + h] = ab;
  qq0[(size_t)b * NH + h] = (float)a0;
}

__global__ __launch_bounds__(256, 4)
void k_a2v3(const float* __restrict__ cv, const float* __restrict__ M2T,
            double* __restrict__ A2) {
  const int b  = blockIdx.x >> 3;
  const int s0 = (blockIdx.x & 7) << 5;
  const int t  = threadIdx.x;
  const int h  = t >> 1;
  const int kh = t & 1;
  const int b256 = b << 8;
  __shared__ float cvS[32][132];
  for (int idx = t; idx < 32 * NE; idx += 256) {
    int r = idx >> 7, c = idx & 127;
    cvS[r][c] = cv[((size_t)(b256 + s0 + r)) * NE + c];
  }
  __syncthreads();
  float4 m2r[16];
  {
    const float4* m2p = (const float4*)(M2T + (size_t)h * NE + kh * 64);
#pragma unroll
    for (int q = 0; q < 16; ++q) m2r[q] = m2p[q];
  }
#pragma unroll 2
  for (int sLoc = 0; sLoc < 32; ++sLoc) {
    const float4* cr4 = ((const float4*)&cvS[sLoc][0]) + kh * 16;
    double c0 = 0.0, c1 = 0.0;
#pragma unroll
    for (int q = 0; q < 16; q += 2) {
      c0 += dot4d(cr4[q],     m2r[q]);
      c1 += dot4d(cr4[q + 1], m2r[q + 1]);
    }
    double s = c0 + c1;
    s += __shfl_xor(s, 1, 64);
    if (kh == 0)
      A2[((size_t)(b256 + s0 + sLoc)) * NH + h] = s;
  }
}

// ======================= main decode kernel: ONE barrier per step =======================
struct MainSh1 {
  alignas(16) float  qq[NH];
  alignas(16) float  vvf[NH];
  float  logitArr[NS];
  alignas(8)  double base128[NH];
  uint2  keyL[NSTEPS];
  float  redV[2][8];
  float  redS[2][8];
  int    redI[2][8];
  alignas(16) float refScr[2][NE];
  int    sRowId[2];
};

struct PreSh {
  float cvS[NS][33];
  float wS[32][NH];
};

__global__ __launch_bounds__(512, 4)
void decode_1b(const float* __restrict__ cv,
               const float* __restrict__ mask_in,
               const float* __restrict__ Wref,
               const float* __restrict__ vvec,
               const double* __restrict__ qqbase,
               const float* __restrict__ M1T,
               const float* __restrict__ qq0,
               const double* __restrict__ A2,
               float* __restrict__ out) {
  const int b = blockIdx.x;
  const int t = threadIdx.x;
  const int b256 = b << 8;
  const int w = t >> 6, l = t & 63;
  const int i = (w << 5) | (l >> 1);     // list position (pair of adjacent lanes)
  const int hHalf = l & 1;
  const int hb = hHalf << 6;
  const int h0 = l << 1;                 // this lane's qq-write pair

  __shared__ union { PreSh pre; MainSh1 m; } sh;
  __shared__ short rowId0[NS];
  __shared__ int tmp8[4], nActSh0;

  // ---------- build initial active-row list (registers across barrier) ----------
  bool act0 = false; int preCnt = 0;
  if (t < NS) {
    act0 = !((t == 0) || (mask_in[(size_t)b256 + t] > 0.0f));
    uint64_t mb = __ballot(act0);
    int lane = t & 63, wv = t >> 6;
    preCnt = __popcll(mb & (((uint64_t)1 << lane) - 1));
    if (lane == 0) tmp8[wv] = (int)__popcll(mb);
  }
  __syncthreads();
  if (t < NS && act0) {
    int base = 0;
    for (int k = 0; k < (t >> 6); ++k) base += tmp8[k];
    rowId0[base + preCnt] = (short)t;
  }
  if (t == 0) nActSh0 = tmp8[0] + tmp8[1] + tmp8[2] + tmp8[3];
  __syncthreads();
  const int nAct0 = nActSh0;

  // ---------- Phase 1: refr = ref[myRow0][hb..hb+64) (bit-identical chunking) ----------
  int myRow = (i < nAct0) ? (int)rowId0[i] : 0;
  float refr[64];
#pragma unroll
  for (int j = 0; j < 64; ++j) refr[j] = 0.0f;

  for (int ec = 0; ec < 4; ++ec) {
    __syncthreads();
    for (int ii = t; ii < 32 * NH; ii += 512) {
      int r = ii >> 7, c = ii & 127;
      sh.pre.wS[r][c] = Wref[(ec * 32 + r) * NH + c];
    }
    for (int ii = t; ii < NS * 32; ii += 512) {
      int r = ii >> 5, c = ii & 31;
      sh.pre.cvS[r][c] = cv[((size_t)b256 + r) * NE + ec * 32 + c];
    }
    __syncthreads();
    for (int hc = 0; hc < 8; ++hc) {
      double a[8] = {0,0,0,0,0,0,0,0};
      for (int e = 0; e < 32; ++e) {
        double cd = (double)sh.pre.cvS[myRow][e];
        const float* wp = &sh.pre.wS[e][hb + hc * 8];
#pragma unroll
        for (int j = 0; j < 8; ++j) a[j] += cd * (double)wp[j];
      }
#pragma unroll
      for (int j = 0; j < 8; ++j) refr[hc * 8 + j] += (float)a[j];
    }
  }
  __syncthreads();  // pre dead, m live

  // ---------- prologue ----------
  if (t < NSTEPS) {
    uint32_t o0, o1;
    tf2x32(0u, 42u, 0u, (uint32_t)t, o0, o1);
    sh.m.keyL[t] = make_uint2(o0, o1);
  }
  if (t < NH) {
    sh.m.vvf[t] = vvec[t];
    sh.m.qq[t] = qq0[(size_t)b * NH + t];
  }
  __syncthreads();

  float g = 0.0f;
  if (i < nAct0)
    g = gumbel_of(sh.m.keyL[0], (uint32_t)(b256 + myRow));
  bool adoptNext = false;

  // ---------- 255 decode steps, ONE barrier each (two at step 0) ----------
  for (int step = 0; step < NSTEPS; ++step) {
    const int par = step & 1;
    const int nA = nAct0 - step;
    const bool active = (i < nA);

    // consume adoption decided last step (scratch parity = (step-1)&1 = par^1)
    if (adoptNext) {
      myRow = sh.m.sRowId[par ^ 1];
      const float4* rs4 = (const float4*)(&sh.m.refScr[par ^ 1][hb]);
#pragma unroll
      for (int q = 0; q < 16; ++q) {
        float4 v4 = rs4[q];
        refr[4 * q + 0] = v4.x; refr[4 * q + 1] = v4.y;
        refr[4 * q + 2] = v4.z; refr[4 * q + 3] = v4.w;
      }
      adoptNext = false;
    }
    // donor (always position nA-1) hands off unconditionally, pre-barrier
    if (active && i == nA - 1) {
      float4* rs4 = (float4*)(&sh.m.refScr[par][hb]);
#pragma unroll
      for (int q = 0; q < 16; ++q)
        rs4[q] = make_float4(refr[4 * q + 0], refr[4 * q + 1],
                             refr[4 * q + 2], refr[4 * q + 3]);
      sh.m.sRowId[par] = myRow;
    }

    // tanh partial over this thread's 64-wide h-slice
    double accH = 0.0;
    if (active) {
      double a0 = 0, a1 = 0, a2 = 0, a3 = 0;
      const float4* qq4 = (const float4*)(sh.m.qq + hb);
      const float4* vv4 = (const float4*)(sh.m.vvf + hb);
#pragma unroll
      for (int q = 0; q < 16; ++q) {
        float4 qv = qq4[q];
        float4 wv = vv4[q];
        a0 += (double)nr_tanh(qv.x + refr[4 * q + 0]) * (double)wv.x;
        a1 += (double)nr_tanh(qv.y + refr[4 * q + 1]) * (double)wv.y;
        a2 += (double)nr_tanh(qv.z + refr[4 * q + 2]) * (double)wv.z;
        a3 += (double)nr_tanh(qv.w + refr[4 * q + 3]) * (double)wv.w;
      }
      accH = (a0 + a1) + (a2 + a3);
    }
    double other = __shfl_xor(accH, 1, 64);
    float val = SENT_NEG; int bR = 0x7fffffff; float term = 0.0f;
    if (active) {
      double tot = hHalf ? (other + accH) : (accH + other);   // low + high
      float u_ = (float)tot;
      float logit = 10.0f * (float)tanh((double)u_);
      if (!hHalf) {
        sh.m.logitArr[myRow] = logit;
        term = expf(logit);             // each row counted once in lse
      }
      val = logit + g;
      bR = myRow;
    }

    // wave reduce (rows duplicated across pair; terms zero on odd lanes)
    float bvv = val; float bss = term;
#pragma unroll
    for (int mm = 1; mm <= 32; mm <<= 1) {
      float ov = __shfl_xor(bvv, mm, 64);
      int   oR = __shfl_xor(bR,  mm, 64);
      float os = __shfl_xor(bss, mm, 64);
      bss += os;
      if (ov > bvv || (ov == bvv && oR < bR)) { bvv = ov; bR = oR; }
    }

    const bool waveNext = ((w << 5) < nA - 1) && (step + 1 < NSTEPS);

    // candidate A2 prefetch (wave-local winner) for the qq write below
    double pf0 = 0.0, pf1 = 0.0; bool havePf = false;
    if (waveNext && step > 0 && (unsigned)bR <= 255u) {
      const double* ap = A2 + (size_t)(b256 + bR) * NH + h0;
      pf0 = ap[0]; pf1 = ap[1]; havePf = true;
    }

    if (l == 0) {
      sh.m.redV[par][w] = bvv; sh.m.redI[par][w] = bR; sh.m.redS[par][w] = bss;
    }
    __syncthreads();  // THE barrier

    float BV = sh.m.redV[par][0]; int BR_ = sh.m.redI[par][0];
#pragma unroll
    for (int k = 1; k < 8; ++k) {
      float ov = sh.m.redV[par][k]; int oR = sh.m.redI[par][k];
      if (ov > BV || (ov == BV && oR < BR_)) { BV = ov; BR_ = oR; }
    }
    if ((unsigned)BR_ > 255u) BR_ = 0;
    const int BI = BR_;

    if (t == 0) {
      float SS = (sh.m.redS[par][0] + sh.m.redS[par][1]) + (sh.m.redS[par][2] + sh.m.redS[par][3]);
      SS += (sh.m.redS[par][4] + sh.m.redS[par][5]) + (sh.m.redS[par][6] + sh.m.redS[par][7]);
      float lp = sh.m.logitArr[BI] - (float)log((double)SS);
      out[(size_t)b * NSTEPS + step] = (float)BI;
      out[(size_t)NBATCH * NSTEPS + (size_t)b * NSTEPS + step] = lp;
    }

    // register-resident compaction: adopter = pair whose row was selected
    adoptNext = active && (myRow == BI) && (i != nA - 1);

    // next-step gumbel
    if (step + 1 < NSTEPS && i < nA - 1) {
      int ridN = adoptNext ? sh.m.sRowId[par] : myRow;
      g = gumbel_of(sh.m.keyL[step + 1], (uint32_t)(b256 + ridN));
    }

    // ---- qq for next step: every needed wave writes the FULL row itself ----
    if (step == 0) {
      if (NSTEPS > 1) {
        // base128 = qqbase + cv[BI0] @ M1T (one-time, cross-thread split)
        const int hq = t >> 2, kq = t & 3;
        const float4* hrow = (const float4*)(cv + (size_t)(b256 + BI) * NE + kq * 32);
        const float4* m1p  = (const float4*)(M1T + (size_t)hq * NE + kq * 32);
        double am = dot32(hrow, m1p);
        am += __shfl_xor(am, 1, 64);
        am += __shfl_xor(am, 2, 64);
        if (kq == 0)
          sh.m.base128[hq] = qqbase[(size_t)b * NH + hq] + am;
        __syncthreads();  // step-0 only: base128 ready
        if (waveNext) {
          double a0v = A2[(size_t)(b256 + BI) * NH + h0];
          double a1v = A2[(size_t)(b256 + BI) * NH + h0 + 1];
          sh.m.qq[h0]     = (float)(sh.m.base128[h0]     + a0v);
          sh.m.qq[h0 + 1] = (float)(sh.m.base128[h0 + 1] + a1v);
        }
      }
    } else if (waveNext) {
      double a0v, a1v;
      if (havePf && bR == BI) { a0v = pf0; a1v = pf1; }
      else {
        a0v = A2[(size_t)(b256 + BI) * NH + h0];
        a1v = A2[(size_t)(b256 + BI) * NH + h0 + 1];
      }
      sh.m.qq[h0]     = (float)(sh.m.base128[h0]     + a0v);
      sh.m.qq[h0 + 1] = (float)(sh.m.base128[h0 + 1] + a1v);
    }
    // no trailing barrier: each wave reads only its own qq writes next step
  }
}

// ======================= round-2 passing kernel (no-ws fallback, unchanged) ==========
__device__ __forceinline__ float fast_tanh_ref(float x) {
  const float Chi = 2.8853900432586670f;
  const float Clo = 3.8519259822379735e-08f;
  float m = fmaf(x, Chi, x * Clo);
  float tt = exp2f(m);
  return 1.0f - 2.0f / (tt + 1.0f);
}

struct MainShR {
  float  query[NE];
  float  qq[NH];
  float  hbar[NE];
  float  inith[NE];
  float  hcur[NE];
  alignas(16) double vvd[NH];
  float  logitArr[NS];
  float  maskArr[NS];
  uint2  keyL[NSTEPS];
  float  meanv[NE];
  float  redV[4];
  int    redI[4];
  double redS[4];
  int    idxSh;
};
struct PreShR {
  float cvS[NS][33];
  float wS[32][NH];
};

__global__ __launch_bounds__(256, 2)
void decoder_kernel_ref(const float* __restrict__ cv, const float* __restrict__ mask_in,
                        const float* __restrict__ liw, const float* __restrict__ Wc,
                        const float* __restrict__ bc, const float* __restrict__ Wv,
                        const float* __restrict__ bv, const float* __restrict__ Wq,
                        const float* __restrict__ Wref, const float* __restrict__ vvec,
                        float* __restrict__ out) {
  const int b = blockIdx.x;
  const int t = threadIdx.x;
  const int b256 = b << 8;
  __shared__ union { PreShR pre; MainShR m; } sh;

  float refr[NH];
#pragma unroll
  for (int h = 0; h < NH; ++h) refr[h] = 0.0f;
  for (int ec = 0; ec < 4; ++ec) {
    const int e0 = ec * 32;
    __syncthreads();
    for (int i = t; i < 32 * NH; i += 256) {
      int r = i >> 7, h = i & 127;
      sh.pre.wS[r][h] = Wref[(e0 + r) * NH + h];
    }
    for (int i = t; i < NS * 32; i += 256) {
      int s2 = i >> 5, j = i & 31;
      sh.pre.cvS[s2][j] = cv[((size_t)b256 + s2) * NE + e0 + j];
    }
    __syncthreads();
#pragma unroll
    for (int hc = 0; hc < 16; ++hc) {
      double a[8] = {0,0,0,0,0,0,0,0};
      for (int e = 0; e < 32; ++e) {
        double cd = (double)sh.pre.cvS[t][e];
#pragma unroll
        for (int j = 0; j < 8; ++j) a[j] += cd * (double)sh.pre.wS[e][hc * 8 + j];
      }
#pragma unroll
      for (int j = 0; j < 8; ++j) refr[hc * 8 + j] += (float)a[j];
    }
  }
  __syncthreads();

  if (t < NSTEPS) {
    uint32_t o0, o1;
    tf2x32(0u, 42u, 0u, (uint32_t)t, o0, o1);
    sh.m.keyL[t] = make_uint2(o0, o1);
  }
  if (t < NH) sh.m.vvd[t] = (double)vvec[t];
  sh.m.maskArr[t] = (mask_in[(size_t)b256 + t] > 0.0f || t == 0) ? 1.0f : 0.0f;
  if (t < NE) {
    double s64 = 0.0;
    for (int s2 = 0; s2 < NS; ++s2) s64 += (double)cv[((size_t)b256 + s2) * NE + t];
    sh.m.meanv[t] = (float)(s64 * (1.0 / 256.0));
  }
  __syncthreads();
  if (t < NE) {
    double acc = 0.0;
    for (int e = 0; e < NE; ++e) acc += (double)sh.m.meanv[e] * (double)Wc[e * NE + t];
    float hbv = (float)acc + bc[t];
    sh.m.hbar[t] = hbv;
    double acc2 = 0.0;
    for (int k = 0; k < 2 * NE; ++k) acc2 += (double)liw[k] * (double)Wv[k * NE + t];
    float r0 = (float)acc2 + bv[t];
    sh.m.query[t] = hbv + r0;
  }
  __syncthreads();

  for (int step = 0; step < NSTEPS; ++step) {
    if (t < NH) {
      double acc = 0.0;
      for (int k = 0; k < NE; ++k) acc += (double)sh.m.query[k] * (double)Wq[k * NH + t];
      sh.m.qq[t] = (float)acc;
    }
    __syncthreads();

    float logit;
    bool masked = (sh.m.maskArr[t] != 0.0f);
    if (!masked) {
      double a0 = 0.0, a1 = 0.0, a2 = 0.0, a3 = 0.0;
      const float4*  qq4 = (const float4*)sh.m.qq;
      const double2* vv2 = (const double2*)sh.m.vvd;
#pragma unroll
      for (int h4 = 0; h4 < 32; ++h4) {
        float4  q  = qq4[h4];
        double2 va = vv2[2 * h4];
        double2 vb = vv2[2 * h4 + 1];
        a0 += (double)fast_tanh_ref(q.x + refr[4 * h4 + 0]) * va.x;
        a1 += (double)fast_tanh_ref(q.y + refr[4 * h4 + 1]) * va.y;
        a2 += (double)fast_tanh_ref(q.z + refr[4 * h4 + 2]) * vb.x;
        a3 += (double)fast_tanh_ref(q.w + refr[4 * h4 + 3]) * vb.y;
      }
      float u_ = (float)((a0 + a1) + (a2 + a3));
      logit = 10.0f * (float)tanh((double)u_);
    } else {
      logit = NEGINF;
    }
    sh.m.logitArr[t] = logit;

    uint2 key = sh.m.keyL[step];
    uint32_t j = (uint32_t)(b256 + t);
    uint32_t o0, o1;
    tf2x32(key.x, key.y, 0u, j, o0, o1);
    uint32_t bits = o0 ^ o1;
    float f = __uint_as_float((bits >> 9) | 0x3f800000u) - 1.0f;
    float u = (f == 0.0f) ? 1.17549435e-38f : f;
    float l1 = (float)(-log((double)u));
    float g  = (float)(-log((double)l1));
    float val = logit + g;
    double term = exp((double)logit);

    float bv_ = val; int bi = t; double bs = term;
#pragma unroll
    for (int m = 1; m <= 32; m <<= 1) {
      float  ov = __shfl_xor(bv_, m, 64);
      int    oi = __shfl_xor(bi,  m, 64);
      double os = __shfl_xor(bs,  m, 64);
      if (ov > bv_ || (ov == bv_ && oi < bi)) { bv_ = ov; bi = oi; }
      bs += os;
    }
    int w = t >> 6;
    if ((t & 63) == 0) { sh.m.redV[w] = bv_; sh.m.redI[w] = bi; sh.m.redS[w] = bs; }
    __syncthreads();

    if (t == 0) {
      float BV = sh.m.redV[0]; int BI = sh.m.redI[0];
      for (int k = 1; k < 4; ++k) {
        float ov = sh.m.redV[k]; int oi = sh.m.redI[k];
        if (ov > BV || (ov == BV && oi < BI)) { BV = ov; BI = oi; }
      }
      double SS = ((sh.m.redS[0] + sh.m.redS[1]) + (sh.m.redS[2] + sh.m.redS[3]));
      sh.m.idxSh = BI;
      float lp = sh.m.logitArr[BI] - (float)log(SS);
      out[(size_t)b * NSTEPS + step] = (float)BI;
      out[(size_t)NBATCH * NSTEPS + (size_t)b * NSTEPS + step] = lp;
    }
    __syncthreads();

    int idx = sh.m.idxSh;
    if (t == idx) sh.m.maskArr[t] = 1.0f;
    if (t < NE) {
      float hc = cv[((size_t)b256 + idx) * NE + t];
      sh.m.hcur[t] = hc;
      if (step == 0) sh.m.inith[t] = hc;
    }
    __syncthreads();

    if (t < NE) {
      double acc2 = 0.0;
      for (int k = 0; k < NE; ++k) acc2 += (double)sh.m.inith[k] * (double)Wv[k * NE + t];
      for (int k = 0; k < NE; ++k) acc2 += (double)sh.m.hcur[k] * (double)Wv[(NE + k) * NE + t];
      float mm = (float)acc2 + bv[t];
      sh.m.query[t] = sh.m.hbar[t] + mm;
    }
    __syncthreads();
  }
}

extern "C" void kernel_launch(void* const* d_in, const int* in_sizes, int n_in,
                              void* d_out, int out_size, void* d_ws, size_t ws_size,
                              hipStream_t stream) {
  const float* cv   = (const float*)d_in[0];
  const float* mask = (const float*)d_in[2];
  const float* liw  = (const float*)d_in[3];
  const float* Wc   = (const float*)d_in[4];
  const float* bc   = (const float*)d_in[5];
  const float* Wv   = (const float*)d_in[6];
  const float* bv   = (const float*)d_in[7];
  const float* Wq   = (const float*)d_in[8];
  const float* Wref = (const float*)d_in[9];
  const float* vv   = (const float*)d_in[10];
  (void)in_sizes; (void)n_in; (void)out_size;

  const size_t SZ_QQB = (size_t)NBATCH * NH * sizeof(double);     // 512 KB
  const size_t SZ_M   = (size_t)NE * NH * sizeof(float);          // 64 KB each
  const size_t SZ_QQ0 = (size_t)NBATCH * NH * sizeof(float);      // 256 KB
  const size_t SZ_A2  = (size_t)NBATCH * NS * NH * sizeof(double);// 134 MB
  const size_t need_pre = SZ_QQB + 2 * SZ_M + SZ_QQ0 + 512 + SZ_A2;

  if (ws_size >= need_pre) {
    char* p = (char*)d_ws;
    double* qqbase = (double*)p;            p += SZ_QQB;
    float*  M1T    = (float*)p;             p += SZ_M;
    float*  M2T    = (float*)p;             p += SZ_M;
    float*  qq0    = (float*)p;             p += SZ_QQ0;
    float*  rest0  = (float*)p;             p += 512;
    double* A2     = (double*)p;

    k1_mats<<<257, 128, 0, stream>>>(Wv, Wq, liw, bv, M1T, M2T, rest0);
    k2_base<<<NBATCH, 128, 0, stream>>>(cv, Wc, bc, bv, Wq, rest0, qqbase, qq0);
    k_a2v3<<<NBATCH * 8, 256, 0, stream>>>(cv, M2T, A2);
    decode_1b<<<NBATCH, 512, 0, stream>>>(cv, mask, Wref, vv, qqbase, M1T,
                                          qq0, A2, (float*)d_out);
  } else {
    decoder_kernel_ref<<<NBATCH, 256, 0, stream>>>(cv, mask, liw, Wc, bc, Wv, bv,
                                                   Wq, Wref, vv, (float*)d_out);
  }
}

// Round 11
// 3019.378 us; speedup vs baseline: 1.0150x; 1.0150x over previous
//
#include <hip/hip_runtime.h>
#include <hip/hip_bf16.h>
#include <stdint.h>
#include <math.h>

#define NBATCH 512
#define NS 256
#define NE 128
#define NH 128
#define NSTEPS 255
#define NEGINF -1e8f
#define SENT_NEG -1e30f

// ---------------- threefry2x32 (partitionable path, verified r2..r10) ----------------
__device__ __forceinline__ uint32_t rotl32(uint32_t x, uint32_t r) {
  return (x << r) | (x >> (32u - r));
}

__device__ __forceinline__ void tf2x32(uint32_t k0, uint32_t k1,
                                       uint32_t x0, uint32_t x1,
                                       uint32_t& o0, uint32_t& o1) {
  uint32_t ks2 = k0 ^ k1 ^ 0x1BD11BDAu;
  x0 += k0; x1 += k1;
#define TF_R4(a,b,c,d) \
  x0 += x1; x1 = rotl32(x1,a); x1 ^= x0; \
  x0 += x1; x1 = rotl32(x1,b); x1 ^= x0; \
  x0 += x1; x1 = rotl32(x1,c); x1 ^= x0; \
  x0 += x1; x1 = rotl32(x1,d); x1 ^= x0;
  TF_R4(13,15,26,6)   x0 += k1;  x1 += ks2 + 1u;
  TF_R4(17,29,16,24)  x0 += ks2; x1 += k0 + 2u;
  TF_R4(13,15,26,6)   x0 += k0;  x1 += k1 + 3u;
  TF_R4(17,29,16,24)  x0 += k1;  x1 += ks2 + 4u;
  TF_R4(13,15,26,6)   x0 += ks2; x1 += k0 + 5u;
#undef TF_R4
  o0 = x0; o1 = x1;
}

__device__ __forceinline__ float gumbel_of(uint2 key, uint32_t j) {
  uint32_t o0, o1;
  tf2x32(key.x, key.y, 0u, j, o0, o1);
  uint32_t bits = o0 ^ o1;
  float f = __uint_as_float((bits >> 9) | 0x3f800000u) - 1.0f;
  float u = (f == 0.0f) ? 1.17549435e-38f : f;
  float l1 = -logf(u);
  return -logf(l1);
}

// tanh via hw exp2 + rcp + 1 Newton step (verified exact-index r3..r10)
__device__ __forceinline__ float nr_tanh(float x) {
  const float Chi = 2.8853900432586670f;
  const float Clo = 3.8519259822379735e-08f;
  float m = fmaf(x, Chi, x * Clo);
  m = fminf(m, 126.0f);
  float tt = __builtin_amdgcn_exp2f(m);
  float d  = tt + 1.0f;
  float r  = __builtin_amdgcn_rcpf(d);
  r = r * fmaf(-d, r, 2.0f);
  return fmaf(-2.0f, r, 1.0f);
}

__device__ __forceinline__ double dot32(const float4* __restrict__ a,
                                        const float4* __restrict__ bp) {
  double s = 0.0;
#pragma unroll
  for (int q = 0; q < 8; ++q) {
    float4 x = a[q], y = bp[q];
    s += (double)x.x * (double)y.x + (double)x.y * (double)y.y
       + (double)x.z * (double)y.z + (double)x.w * (double)y.w;
  }
  return s;
}

__device__ __forceinline__ double dot4d(float4 a, float4 b) {
  return ((double)a.x * (double)b.x + (double)a.y * (double)b.y)
       + ((double)a.z * (double)b.z + (double)a.w * (double)b.w);
}

// ======================= precompute kernels =======================
__global__ void k1_mats(const float* __restrict__ Wv, const float* __restrict__ Wq,
                        const float* __restrict__ liw, const float* __restrict__ bvv,
                        float* __restrict__ M1T, float* __restrict__ M2T,
                        float* __restrict__ rest0) {
  int e = blockIdx.x, h = threadIdx.x;
  __shared__ float wrow[NE];
  if (e < 256) {
    wrow[h] = Wv[e * NE + h];
    __syncthreads();
    double a = 0.0;
    for (int k = 0; k < NE; ++k) a += (double)wrow[k] * (double)Wq[k * NH + h];
    if (e < 128) M1T[h * NE + e] = (float)a;
    else         M2T[h * NE + (e - 128)] = (float)a;
  } else {
    double a = 0.0;
    for (int k = 0; k < 2 * NE; ++k) a += (double)liw[k] * (double)Wv[k * NE + h];
    rest0[h] = (float)a + bvv[h];
  }
}

__global__ void k2_base(const float* __restrict__ cv, const float* __restrict__ Wc,
                        const float* __restrict__ bc, const float* __restrict__ bvv,
                        const float* __restrict__ Wq, const float* __restrict__ rest0,
                        double* __restrict__ qqbase, float* __restrict__ qq0) {
  int b = blockIdx.x, h = threadIdx.x;
  int b256 = b << 8;
  __shared__ float meanL[NE], hbarL[NE];
  double ms = 0.0;
  for (int s = 0; s < NS; ++s) ms += (double)cv[((size_t)b256 + s) * NE + h];
  meanL[h] = (float)(ms * (1.0 / 256.0));
  __syncthreads();
  double a = 0.0;
  for (int e = 0; e < NE; ++e) a += (double)meanL[e] * (double)Wc[e * NE + h];
  hbarL[h] = (float)a + bc[h];
  __syncthreads();
  double ab = 0.0, a0 = 0.0;
  for (int k = 0; k < NE; ++k) {
    double w = (double)Wq[k * NH + h];
    ab += (double)(hbarL[k] + bvv[k]) * w;
    a0 += (double)(hbarL[k] + rest0[k]) * w;
  }
  qqbase[(size_t)b * NH + h] = ab;
  qq0[(size_t)b * NH + h] = (float)a0;
}

__global__ __launch_bounds__(256, 4)
void k_a2v3(const float* __restrict__ cv, const float* __restrict__ M2T,
            double* __restrict__ A2) {
  const int b  = blockIdx.x >> 3;
  const int s0 = (blockIdx.x & 7) << 5;
  const int t  = threadIdx.x;
  const int h  = t >> 1;
  const int kh = t & 1;
  const int b256 = b << 8;
  __shared__ float cvS[32][132];
  for (int idx = t; idx < 32 * NE; idx += 256) {
    int r = idx >> 7, c = idx & 127;
    cvS[r][c] = cv[((size_t)(b256 + s0 + r)) * NE + c];
  }
  __syncthreads();
  float4 m2r[16];
  {
    const float4* m2p = (const float4*)(M2T + (size_t)h * NE + kh * 64);
#pragma unroll
    for (int q = 0; q < 16; ++q) m2r[q] = m2p[q];
  }
#pragma unroll 2
  for (int sLoc = 0; sLoc < 32; ++sLoc) {
    const float4* cr4 = ((const float4*)&cvS[sLoc][0]) + kh * 16;
    double c0 = 0.0, c1 = 0.0;
#pragma unroll
    for (int q = 0; q < 16; q += 2) {
      c0 += dot4d(cr4[q],     m2r[q]);
      c1 += dot4d(cr4[q + 1], m2r[q + 1]);
    }
    double s = c0 + c1;
    s += __shfl_xor(s, 1, 64);
    if (kh == 0)
      A2[((size_t)(b256 + s0 + sLoc)) * NH + h] = s;
  }
}

// k_gum: G[b][step][row] = gumbel for (keys[step], b*256+row). Bit-identical
// threefry + libm logf to the in-loop version (just moved off the decode path).
__global__ __launch_bounds__(256)
void k_gum(float* __restrict__ G) {
  const int b = blockIdx.x, step = blockIdx.y, r = threadIdx.x;
  uint32_t k0, k1;
  tf2x32(0u, 42u, 0u, (uint32_t)step, k0, k1);
  float g = gumbel_of(make_uint2(k0, k1), (uint32_t)((b << 8) + r));
  G[((size_t)b * NSTEPS + step) * NS + r] = g;
}

// ======================= main decode kernel: ONE barrier per step =======================
struct MainSh1 {
  alignas(16) float  qq[NH];
  alignas(16) float  vvf[NH];
  float  logitArr[NS];
  alignas(8)  double base128[NH];
  uint2  keyL[NSTEPS];
  float  redV[2][8];
  float  redS[2][8];
  int    redI[2][8];
  alignas(16) float refScr[2][NE];
  int    sRowId[2];
};

struct PreSh {
  float cvS[NS][33];
  float wS[32][NH];
};

template <int MODEG>   // 1: gumbel from precomputed G; 0: inline threefry+logf
__global__ __launch_bounds__(512, 4)
void decode_1b(const float* __restrict__ cv,
               const float* __restrict__ mask_in,
               const float* __restrict__ Wref,
               const float* __restrict__ vvec,
               const double* __restrict__ qqbase,
               const float* __restrict__ M1T,
               const float* __restrict__ qq0,
               const double* __restrict__ A2,
               const float* __restrict__ G,
               float* __restrict__ out) {
  const int b = blockIdx.x;
  const int t = threadIdx.x;
  const int b256 = b << 8;
  const int w = t >> 6, l = t & 63;
  const int i = (w << 5) | (l >> 1);     // list position (pair of adjacent lanes)
  const int hHalf = l & 1;
  const int hb = hHalf << 6;
  const int h0 = l << 1;                 // this lane's qq-write pair
  const float LOG2E = 1.4426950408889634f;

  __shared__ union { PreSh pre; MainSh1 m; } sh;
  __shared__ short rowId0[NS];
  __shared__ int tmp8[4], nActSh0;

  // ---------- build initial active-row list ----------
  bool act0 = false; int preCnt = 0;
  if (t < NS) {
    act0 = !((t == 0) || (mask_in[(size_t)b256 + t] > 0.0f));
    uint64_t mb = __ballot(act0);
    int lane = t & 63, wv = t >> 6;
    preCnt = __popcll(mb & (((uint64_t)1 << lane) - 1));
    if (lane == 0) tmp8[wv] = (int)__popcll(mb);
  }
  __syncthreads();
  if (t < NS && act0) {
    int base = 0;
    for (int k = 0; k < (t >> 6); ++k) base += tmp8[k];
    rowId0[base + preCnt] = (short)t;
  }
  if (t == 0) nActSh0 = tmp8[0] + tmp8[1] + tmp8[2] + tmp8[3];
  __syncthreads();
  const int nAct0 = nActSh0;

  // ---------- Phase 1: refr = ref[myRow0][hb..hb+64) (bit-identical chunking) ----------
  int myRow = (i < nAct0) ? (int)rowId0[i] : 0;
  float refr[64];
#pragma unroll
  for (int j = 0; j < 64; ++j) refr[j] = 0.0f;

  for (int ec = 0; ec < 4; ++ec) {
    __syncthreads();
    for (int ii = t; ii < 32 * NH; ii += 512) {
      int r = ii >> 7, c = ii & 127;
      sh.pre.wS[r][c] = Wref[(ec * 32 + r) * NH + c];
    }
    for (int ii = t; ii < NS * 32; ii += 512) {
      int r = ii >> 5, c = ii & 31;
      sh.pre.cvS[r][c] = cv[((size_t)b256 + r) * NE + ec * 32 + c];
    }
    __syncthreads();
    for (int hc = 0; hc < 8; ++hc) {
      double a[8] = {0,0,0,0,0,0,0,0};
      for (int e = 0; e < 32; ++e) {
        double cd = (double)sh.pre.cvS[myRow][e];
        const float* wp = &sh.pre.wS[e][hb + hc * 8];
#pragma unroll
        for (int j = 0; j < 8; ++j) a[j] += cd * (double)wp[j];
      }
#pragma unroll
      for (int j = 0; j < 8; ++j) refr[hc * 8 + j] += (float)a[j];
    }
  }
  __syncthreads();  // pre dead, m live

  // ---------- prologue ----------
  if (t < NSTEPS) {
    uint32_t o0, o1;
    tf2x32(0u, 42u, 0u, (uint32_t)t, o0, o1);
    sh.m.keyL[t] = make_uint2(o0, o1);
  }
  if (t < NH) {
    sh.m.vvf[t] = vvec[t];
    sh.m.qq[t] = qq0[(size_t)b * NH + t];
  }
  __syncthreads();

  float g = 0.0f;
  if (i < nAct0) {
    if (MODEG) g = G[((size_t)b * NSTEPS + 0) * NS + myRow];
    else       g = gumbel_of(sh.m.keyL[0], (uint32_t)(b256 + myRow));
  }
  bool adoptNext = false;

  // ---------- 255 decode steps, ONE barrier each (two at step 0) ----------
  for (int step = 0; step < NSTEPS; ++step) {
    const int par = step & 1;
    const int nA = nAct0 - step;
    const bool active = (i < nA);

    // consume adoption decided last step
    if (adoptNext) {
      myRow = sh.m.sRowId[par ^ 1];
      const float4* rs4 = (const float4*)(&sh.m.refScr[par ^ 1][hb]);
#pragma unroll
      for (int q = 0; q < 16; ++q) {
        float4 v4 = rs4[q];
        refr[4 * q + 0] = v4.x; refr[4 * q + 1] = v4.y;
        refr[4 * q + 2] = v4.z; refr[4 * q + 3] = v4.w;
      }
      adoptNext = false;
    }
    // donor (always position nA-1) hands off unconditionally, pre-barrier
    if (active && i == nA - 1) {
      float4* rs4 = (float4*)(&sh.m.refScr[par][hb]);
#pragma unroll
      for (int q = 0; q < 16; ++q)
        rs4[q] = make_float4(refr[4 * q + 0], refr[4 * q + 1],
                             refr[4 * q + 2], refr[4 * q + 3]);
      sh.m.sRowId[par] = myRow;
    }

    // tanh partial over this thread's 64-wide h-slice
    double accH = 0.0;
    if (active) {
      double a0 = 0, a1 = 0, a2 = 0, a3 = 0;
      const float4* qq4 = (const float4*)(sh.m.qq + hb);
      const float4* vv4 = (const float4*)(sh.m.vvf + hb);
#pragma unroll
      for (int q = 0; q < 16; ++q) {
        float4 qv = qq4[q];
        float4 wv = vv4[q];
        a0 += (double)nr_tanh(qv.x + refr[4 * q + 0]) * (double)wv.x;
        a1 += (double)nr_tanh(qv.y + refr[4 * q + 1]) * (double)wv.y;
        a2 += (double)nr_tanh(qv.z + refr[4 * q + 2]) * (double)wv.z;
        a3 += (double)nr_tanh(qv.w + refr[4 * q + 3]) * (double)wv.w;
      }
      accH = (a0 + a1) + (a2 + a3);
    }
    double other = __shfl_xor(accH, 1, 64);
    float val = SENT_NEG; int bR = 0x7fffffff; float term = 0.0f;
    if (active) {
      double tot = hHalf ? (other + accH) : (accH + other);   // low + high
      float u_ = (float)tot;
      float logit = 10.0f * (float)tanh((double)u_);
      if (!hHalf) {
        sh.m.logitArr[myRow] = logit;
        term = __builtin_amdgcn_exp2f(logit * LOG2E);   // lse term (lp-only, loose tol)
      }
      val = logit + g;
      bR = myRow;
    }

    // wave reduce (rows duplicated across pair; terms zero on odd lanes)
    float bvv = val; float bss = term;
#pragma unroll
    for (int mm = 1; mm <= 32; mm <<= 1) {
      float ov = __shfl_xor(bvv, mm, 64);
      int   oR = __shfl_xor(bR,  mm, 64);
      float os = __shfl_xor(bss, mm, 64);
      bss += os;
      if (ov > bvv || (ov == bvv && oR < bR)) { bvv = ov; bR = oR; }
    }
    if (l == 0) {
      sh.m.redV[par][w] = bvv; sh.m.redI[par][w] = bR; sh.m.redS[par][w] = bss;
    }
    __syncthreads();  // THE barrier (LDS-only drain: no HBM loads outstanding)

    float BV = sh.m.redV[par][0]; int BR_ = sh.m.redI[par][0];
#pragma unroll
    for (int k = 1; k < 8; ++k) {
      float ov = sh.m.redV[par][k]; int oR = sh.m.redI[par][k];
      if (ov > BV || (ov == BV && oR < BR_)) { BV = ov; BR_ = oR; }
    }
    if ((unsigned)BR_ > 255u) BR_ = 0;
    const int BI = BR_;

    const bool waveNext = ((w << 5) < nA - 1) && (step + 1 < NSTEPS);

    // EARLY A2 issue (post-barrier): latency overlaps out-write/gumbel/bookkeeping
    double a0v = 0.0, a1v = 0.0;
    if (step > 0 && waveNext) {
      const double* ap = A2 + (size_t)(b256 + BI) * NH + h0;
      a0v = ap[0]; a1v = ap[1];
    }

    if (t == 0) {
      float SS = (sh.m.redS[par][0] + sh.m.redS[par][1]) + (sh.m.redS[par][2] + sh.m.redS[par][3]);
      SS += (sh.m.redS[par][4] + sh.m.redS[par][5]) + (sh.m.redS[par][6] + sh.m.redS[par][7]);
      float lp = sh.m.logitArr[BI] - (float)log((double)SS);
      out[(size_t)b * NSTEPS + step] = (float)BI;
      out[(size_t)NBATCH * NSTEPS + (size_t)b * NSTEPS + step] = lp;
    }

    // register-resident compaction: adopter = pair whose row was selected
    adoptNext = active && (myRow == BI) && (i != nA - 1);

    // next-step gumbel
    if (step + 1 < NSTEPS && i < nA - 1) {
      int ridN = adoptNext ? sh.m.sRowId[par] : myRow;
      if (MODEG) g = G[((size_t)b * NSTEPS + (step + 1)) * NS + ridN];
      else       g = gumbel_of(sh.m.keyL[step + 1], (uint32_t)(b256 + ridN));
    }

    // ---- qq for next step: every needed wave writes the FULL row itself ----
    if (step == 0) {
      if (NSTEPS > 1) {
        const int hq = t >> 2, kq = t & 3;
        const float4* hrow = (const float4*)(cv + (size_t)(b256 + BI) * NE + kq * 32);
        const float4* m1p  = (const float4*)(M1T + (size_t)hq * NE + kq * 32);
        double am = dot32(hrow, m1p);
        am += __shfl_xor(am, 1, 64);
        am += __shfl_xor(am, 2, 64);
        if (kq == 0)
          sh.m.base128[hq] = qqbase[(size_t)b * NH + hq] + am;
        __syncthreads();  // step-0 only: base128 ready
        if (waveNext) {
          double b0 = A2[(size_t)(b256 + BI) * NH + h0];
          double b1 = A2[(size_t)(b256 + BI) * NH + h0 + 1];
          sh.m.qq[h0]     = (float)(sh.m.base128[h0]     + b0);
          sh.m.qq[h0 + 1] = (float)(sh.m.base128[h0 + 1] + b1);
        }
      }
    } else if (waveNext) {
      sh.m.qq[h0]     = (float)(sh.m.base128[h0]     + a0v);
      sh.m.qq[h0 + 1] = (float)(sh.m.base128[h0 + 1] + a1v);
    }
    // no trailing barrier: each wave reads only its own qq writes next step
  }
}

// ======================= round-2 passing kernel (no-ws fallback, unchanged) ==========
__device__ __forceinline__ float fast_tanh_ref(float x) {
  const float Chi = 2.8853900432586670f;
  const float Clo = 3.8519259822379735e-08f;
  float m = fmaf(x, Chi, x * Clo);
  float tt = exp2f(m);
  return 1.0f - 2.0f / (tt + 1.0f);
}

struct MainShR {
  float  query[NE];
  float  qq[NH];
  float  hbar[NE];
  float  inith[NE];
  float  hcur[NE];
  alignas(16) double vvd[NH];
  float  logitArr[NS];
  float  maskArr[NS];
  uint2  keyL[NSTEPS];
  float  meanv[NE];
  float  redV[4];
  int    redI[4];
  double redS[4];
  int    idxSh;
};
struct PreShR {
  float cvS[NS][33];
  float wS[32][NH];
};

__global__ __launch_bounds__(256, 2)
void decoder_kernel_ref(const float* __restrict__ cv, const float* __restrict__ mask_in,
                        const float* __restrict__ liw, const float* __restrict__ Wc,
                        const float* __restrict__ bc, const float* __restrict__ Wv,
                        const float* __restrict__ bv, const float* __restrict__ Wq,
                        const float* __restrict__ Wref, const float* __restrict__ vvec,
                        float* __restrict__ out) {
  const int b = blockIdx.x;
  const int t = threadIdx.x;
  const int b256 = b << 8;
  __shared__ union { PreShR pre; MainShR m; } sh;

  float refr[NH];
#pragma unroll
  for (int h = 0; h < NH; ++h) refr[h] = 0.0f;
  for (int ec = 0; ec < 4; ++ec) {
    const int e0 = ec * 32;
    __syncthreads();
    for (int i = t; i < 32 * NH; i += 256) {
      int r = i >> 7, h = i & 127;
      sh.pre.wS[r][h] = Wref[(e0 + r) * NH + h];
    }
    for (int i = t; i < NS * 32; i += 256) {
      int s2 = i >> 5, j = i & 31;
      sh.pre.cvS[s2][j] = cv[((size_t)b256 + s2) * NE + e0 + j];
    }
    __syncthreads();
#pragma unroll
    for (int hc = 0; hc < 16; ++hc) {
      double a[8] = {0,0,0,0,0,0,0,0};
      for (int e = 0; e < 32; ++e) {
        double cd = (double)sh.pre.cvS[t][e];
#pragma unroll
        for (int j = 0; j < 8; ++j) a[j] += cd * (double)sh.pre.wS[e][hc * 8 + j];
      }
#pragma unroll
      for (int j = 0; j < 8; ++j) refr[hc * 8 + j] += (float)a[j];
    }
  }
  __syncthreads();

  if (t < NSTEPS) {
    uint32_t o0, o1;
    tf2x32(0u, 42u, 0u, (uint32_t)t, o0, o1);
    sh.m.keyL[t] = make_uint2(o0, o1);
  }
  if (t < NH) sh.m.vvd[t] = (double)vvec[t];
  sh.m.maskArr[t] = (mask_in[(size_t)b256 + t] > 0.0f || t == 0) ? 1.0f : 0.0f;
  if (t < NE) {
    double s64 = 0.0;
    for (int s2 = 0; s2 < NS; ++s2) s64 += (double)cv[((size_t)b256 + s2) * NE + t];
    sh.m.meanv[t] = (float)(s64 * (1.0 / 256.0));
  }
  __syncthreads();
  if (t < NE) {
    double acc = 0.0;
    for (int e = 0; e < NE; ++e) acc += (double)sh.m.meanv[e] * (double)Wc[e * NE + t];
    float hbv = (float)acc + bc[t];
    sh.m.hbar[t] = hbv;
    double acc2 = 0.0;
    for (int k = 0; k < 2 * NE; ++k) acc2 += (double)liw[k] * (double)Wv[k * NE + t];
    float r0 = (float)acc2 + bv[t];
    sh.m.query[t] = hbv + r0;
  }
  __syncthreads();

  for (int step = 0; step < NSTEPS; ++step) {
    if (t < NH) {
      double acc = 0.0;
      for (int k = 0; k < NE; ++k) acc += (double)sh.m.query[k] * (double)Wq[k * NH + t];
      sh.m.qq[t] = (float)acc;
    }
    __syncthreads();

    float logit;
    bool masked = (sh.m.maskArr[t] != 0.0f);
    if (!masked) {
      double a0 = 0.0, a1 = 0.0, a2 = 0.0, a3 = 0.0;
      const float4*  qq4 = (const float4*)sh.m.qq;
      const double2* vv2 = (const double2*)sh.m.vvd;
#pragma unroll
      for (int h4 = 0; h4 < 32; ++h4) {
        float4  q  = qq4[h4];
        double2 va = vv2[2 * h4];
        double2 vb = vv2[2 * h4 + 1];
        a0 += (double)fast_tanh_ref(q.x + refr[4 * h4 + 0]) * va.x;
        a1 += (double)fast_tanh_ref(q.y + refr[4 * h4 + 1]) * va.y;
        a2 += (double)fast_tanh_ref(q.z + refr[4 * h4 + 2]) * vb.x;
        a3 += (double)fast_tanh_ref(q.w + refr[4 * h4 + 3]) * vb.y;
      }
      float u_ = (float)((a0 + a1) + (a2 + a3));
      logit = 10.0f * (float)tanh((double)u_);
    } else {
      logit = NEGINF;
    }
    sh.m.logitArr[t] = logit;

    uint2 key = sh.m.keyL[step];
    uint32_t j = (uint32_t)(b256 + t);
    uint32_t o0, o1;
    tf2x32(key.x, key.y, 0u, j, o0, o1);
    uint32_t bits = o0 ^ o1;
    float f = __uint_as_float((bits >> 9) | 0x3f800000u) - 1.0f;
    float u = (f == 0.0f) ? 1.17549435e-38f : f;
    float l1 = (float)(-log((double)u));
    float g  = (float)(-log((double)l1));
    float val = logit + g;
    double term = exp((double)logit);

    float bv_ = val; int bi = t; double bs = term;
#pragma unroll
    for (int m = 1; m <= 32; m <<= 1) {
      float  ov = __shfl_xor(bv_, m, 64);
      int    oi = __shfl_xor(bi,  m, 64);
      double os = __shfl_xor(bs,  m, 64);
      if (ov > bv_ || (ov == bv_ && oi < bi)) { bv_ = ov; bi = oi; }
      bs += os;
    }
    int w = t >> 6;
    if ((t & 63) == 0) { sh.m.redV[w] = bv_; sh.m.redI[w] = bi; sh.m.redS[w] = bs; }
    __syncthreads();

    if (t == 0) {
      float BV = sh.m.redV[0]; int BI = sh.m.redI[0];
      for (int k = 1; k < 4; ++k) {
        float ov = sh.m.redV[k]; int oi = sh.m.redI[k];
        if (ov > BV || (ov == BV && oi < BI)) { BV = ov; BI = oi; }
      }
      double SS = ((sh.m.redS[0] + sh.m.redS[1]) + (sh.m.redS[2] + sh.m.redS[3]));
      sh.m.idxSh = BI;
      float lp = sh.m.logitArr[BI] - (float)log(SS);
      out[(size_t)b * NSTEPS + step] = (float)BI;
      out[(size_t)NBATCH * NSTEPS + (size_t)b * NSTEPS + step] = lp;
    }
    __syncthreads();

    int idx = sh.m.idxSh;
    if (t == idx) sh.m.maskArr[t] = 1.0f;
    if (t < NE) {
      float hc = cv[((size_t)b256 + idx) * NE + t];
      sh.m.hcur[t] = hc;
      if (step == 0) sh.m.inith[t] = hc;
    }
    __syncthreads();

    if (t < NE) {
      double acc2 = 0.0;
      for (int k = 0; k < NE; ++k) acc2 += (double)sh.m.inith[k] * (double)Wv[k * NE + t];
      for (int k = 0; k < NE; ++k) acc2 += (double)sh.m.hcur[k] * (double)Wv[(NE + k) * NE + t];
      float mm = (float)acc2 + bv[t];
      sh.m.query[t] = sh.m.hbar[t] + mm;
    }
    __syncthreads();
  }
}

extern "C" void kernel_launch(void* const* d_in, const int* in_sizes, int n_in,
                              void* d_out, int out_size, void* d_ws, size_t ws_size,
                              hipStream_t stream) {
  const float* cv   = (const float*)d_in[0];
  const float* mask = (const float*)d_in[2];
  const float* liw  = (const float*)d_in[3];
  const float* Wc   = (const float*)d_in[4];
  const float* bc   = (const float*)d_in[5];
  const float* Wv   = (const float*)d_in[6];
  const float* bv   = (const float*)d_in[7];
  const float* Wq   = (const float*)d_in[8];
  const float* Wref = (const float*)d_in[9];
  const float* vv   = (const float*)d_in[10];
  (void)in_sizes; (void)n_in; (void)out_size;

  const size_t SZ_QQB = (size_t)NBATCH * NH * sizeof(double);      // 512 KB
  const size_t SZ_M   = (size_t)NE * NH * sizeof(float);           // 64 KB each
  const size_t SZ_QQ0 = (size_t)NBATCH * NH * sizeof(float);       // 256 KB
  const size_t SZ_A2  = (size_t)NBATCH * NS * NH * sizeof(double); // 134 MB
  const size_t SZ_G   = (size_t)NBATCH * NSTEPS * NS * sizeof(float); // 133.6 MB
  const size_t need_pre = SZ_QQB + 2 * SZ_M + SZ_QQ0 + 512 + SZ_A2;
  const size_t need_g   = need_pre + SZ_G;

  if (ws_size >= need_pre) {
    char* p = (char*)d_ws;
    double* qqbase = (double*)p;            p += SZ_QQB;
    float*  M1T    = (float*)p;             p += SZ_M;
    float*  M2T    = (float*)p;             p += SZ_M;
    float*  qq0    = (float*)p;             p += SZ_QQ0;
    float*  rest0  = (float*)p;             p += 512;
    double* A2     = (double*)p;            p += SZ_A2;
    float*  G      = (float*)p;

    k1_mats<<<257, 128, 0, stream>>>(Wv, Wq, liw, bv, M1T, M2T, rest0);
    k2_base<<<NBATCH, 128, 0, stream>>>(cv, Wc, bc, bv, Wq, rest0, qqbase, qq0);
    k_a2v3<<<NBATCH * 8, 256, 0, stream>>>(cv, M2T, A2);
    if (ws_size >= need_g) {
      k_gum<<<dim3(NBATCH, NSTEPS), 256, 0, stream>>>(G);
      decode_1b<1><<<NBATCH, 512, 0, stream>>>(cv, mask, Wref, vv, qqbase, M1T,
                                               qq0, A2, G, (float*)d_out);
    } else {
      decode_1b<0><<<NBATCH, 512, 0, stream>>>(cv, mask, Wref, vv, qqbase, M1T,
                                               qq0, A2, nullptr, (float*)d_out);
    }
  } else {
    decoder_kernel_ref<<<NBATCH, 256, 0, stream>>>(cv, mask, liw, Wc, bc, Wv, bv,
                                                   Wq, Wref, vv, (float*)d_out);
  }
}

// Round 12
// 2933.343 us; speedup vs baseline: 1.0448x; 1.0293x over previous
//
#include <hip/hip_runtime.h>
#include <hip/hip_bf16.h>
#include <stdint.h>
#include <math.h>

#define NBATCH 512
#define NS 256
#define NE 128
#define NH 128
#define NSTEPS 255
#define NEGINF -1e8f
#define SENT_NEG -1e30f
#define SENT_NEG2 -3e38f

// ---------------- threefry2x32 (partitionable path, verified r2..r11) ----------------
__device__ __forceinline__ uint32_t rotl32(uint32_t x, uint32_t r) {
  return (x << r) | (x >> (32u - r));
}

__device__ __forceinline__ void tf2x32(uint32_t k0, uint32_t k1,
                                       uint32_t x0, uint32_t x1,
                                       uint32_t& o0, uint32_t& o1) {
  uint32_t ks2 = k0 ^ k1 ^ 0x1BD11BDAu;
  x0 += k0; x1 += k1;
#define TF_R4(a,b,c,d) \
  x0 += x1; x1 = rotl32(x1,a); x1 ^= x0; \
  x0 += x1; x1 = rotl32(x1,b); x1 ^= x0; \
  x0 += x1; x1 = rotl32(x1,c); x1 ^= x0; \
  x0 += x1; x1 = rotl32(x1,d); x1 ^= x0;
  TF_R4(13,15,26,6)   x0 += k1;  x1 += ks2 + 1u;
  TF_R4(17,29,16,24)  x0 += ks2; x1 += k0 + 2u;
  TF_R4(13,15,26,6)   x0 += k0;  x1 += k1 + 3u;
  TF_R4(17,29,16,24)  x0 += k1;  x1 += ks2 + 4u;
  TF_R4(13,15,26,6)   x0 += ks2; x1 += k0 + 5u;
#undef TF_R4
  o0 = x0; o1 = x1;
}

__device__ __forceinline__ float gumbel_of(uint2 key, uint32_t j) {
  uint32_t o0, o1;
  tf2x32(key.x, key.y, 0u, j, o0, o1);
  uint32_t bits = o0 ^ o1;
  float f = __uint_as_float((bits >> 9) | 0x3f800000u) - 1.0f;
  float u = (f == 0.0f) ? 1.17549435e-38f : f;
  float l1 = -logf(u);
  return -logf(l1);
}

// tanh via hw exp2 + rcp + 1 Newton step (verified exact-index r3..r11)
__device__ __forceinline__ float nr_tanh(float x) {
  const float Chi = 2.8853900432586670f;
  const float Clo = 3.8519259822379735e-08f;
  float m = fmaf(x, Chi, x * Clo);
  m = fminf(m, 126.0f);
  float tt = __builtin_amdgcn_exp2f(m);
  float d  = tt + 1.0f;
  float r  = __builtin_amdgcn_rcpf(d);
  r = r * fmaf(-d, r, 2.0f);
  return fmaf(-2.0f, r, 1.0f);
}

__device__ __forceinline__ double dot32(const float4* __restrict__ a,
                                        const float4* __restrict__ bp) {
  double s = 0.0;
#pragma unroll
  for (int q = 0; q < 8; ++q) {
    float4 x = a[q], y = bp[q];
    s += (double)x.x * (double)y.x + (double)x.y * (double)y.y
       + (double)x.z * (double)y.z + (double)x.w * (double)y.w;
  }
  return s;
}

__device__ __forceinline__ double dot4d(float4 a, float4 b) {
  return ((double)a.x * (double)b.x + (double)a.y * (double)b.y)
       + ((double)a.z * (double)b.z + (double)a.w * (double)b.w);
}

// ======================= precompute kernels (unchanged) =======================
__global__ void k1_mats(const float* __restrict__ Wv, const float* __restrict__ Wq,
                        const float* __restrict__ liw, const float* __restrict__ bvv,
                        float* __restrict__ M1T, float* __restrict__ M2T,
                        float* __restrict__ rest0) {
  int e = blockIdx.x, h = threadIdx.x;
  __shared__ float wrow[NE];
  if (e < 256) {
    wrow[h] = Wv[e * NE + h];
    __syncthreads();
    double a = 0.0;
    for (int k = 0; k < NE; ++k) a += (double)wrow[k] * (double)Wq[k * NH + h];
    if (e < 128) M1T[h * NE + e] = (float)a;
    else         M2T[h * NE + (e - 128)] = (float)a;
  } else {
    double a = 0.0;
    for (int k = 0; k < 2 * NE; ++k) a += (double)liw[k] * (double)Wv[k * NE + h];
    rest0[h] = (float)a + bvv[h];
  }
}

__global__ void k2_base(const float* __restrict__ cv, const float* __restrict__ Wc,
                        const float* __restrict__ bc, const float* __restrict__ bvv,
                        const float* __restrict__ Wq, const float* __restrict__ rest0,
                        double* __restrict__ qqbase, float* __restrict__ qq0) {
  int b = blockIdx.x, h = threadIdx.x;
  int b256 = b << 8;
  __shared__ float meanL[NE], hbarL[NE];
  double ms = 0.0;
  for (int s = 0; s < NS; ++s) ms += (double)cv[((size_t)b256 + s) * NE + h];
  meanL[h] = (float)(ms * (1.0 / 256.0));
  __syncthreads();
  double a = 0.0;
  for (int e = 0; e < NE; ++e) a += (double)meanL[e] * (double)Wc[e * NE + h];
  hbarL[h] = (float)a + bc[h];
  __syncthreads();
  double ab = 0.0, a0 = 0.0;
  for (int k = 0; k < NE; ++k) {
    double w = (double)Wq[k * NH + h];
    ab += (double)(hbarL[k] + bvv[k]) * w;
    a0 += (double)(hbarL[k] + rest0[k]) * w;
  }
  qqbase[(size_t)b * NH + h] = ab;
  qq0[(size_t)b * NH + h] = (float)a0;
}

__global__ __launch_bounds__(256, 4)
void k_a2v3(const float* __restrict__ cv, const float* __restrict__ M2T,
            double* __restrict__ A2) {
  const int b  = blockIdx.x >> 3;
  const int s0 = (blockIdx.x & 7) << 5;
  const int t  = threadIdx.x;
  const int h  = t >> 1;
  const int kh = t & 1;
  const int b256 = b << 8;
  __shared__ float cvS[32][132];
  for (int idx = t; idx < 32 * NE; idx += 256) {
    int r = idx >> 7, c = idx & 127;
    cvS[r][c] = cv[((size_t)(b256 + s0 + r)) * NE + c];
  }
  __syncthreads();
  float4 m2r[16];
  {
    const float4* m2p = (const float4*)(M2T + (size_t)h * NE + kh * 64);
#pragma unroll
    for (int q = 0; q < 16; ++q) m2r[q] = m2p[q];
  }
#pragma unroll 2
  for (int sLoc = 0; sLoc < 32; ++sLoc) {
    const float4* cr4 = ((const float4*)&cvS[sLoc][0]) + kh * 16;
    double c0 = 0.0, c1 = 0.0;
#pragma unroll
    for (int q = 0; q < 16; q += 2) {
      c0 += dot4d(cr4[q],     m2r[q]);
      c1 += dot4d(cr4[q + 1], m2r[q + 1]);
    }
    double s = c0 + c1;
    s += __shfl_xor(s, 1, 64);
    if (kh == 0)
      A2[((size_t)(b256 + s0 + sLoc)) * NH + h] = s;
  }
}

__global__ __launch_bounds__(256)
void k_gum(float* __restrict__ G) {
  const int b = blockIdx.x, step = blockIdx.y, r = threadIdx.x;
  uint32_t k0, k1;
  tf2x32(0u, 42u, 0u, (uint32_t)step, k0, k1);
  float g = gumbel_of(make_uint2(k0, k1), (uint32_t)((b << 8) + r));
  G[((size_t)b * NSTEPS + step) * NS + r] = g;
}

// ======================= main decode kernel =======================
struct MainSh1 {
  alignas(16) float  qq[NH];
  alignas(16) float  vvf[NH];
  alignas(8)  double base128[NH];
  uint2  keyL[NSTEPS];
  float  redV[2][8];
  float  redS[2][8];
  float  redL[2][8];
  int    redI[2][8];
  alignas(16) float refScr[2][NE];
  int    sRowId[2];
};

struct PreSh {
  float cvS[NS][33];
  float wS[32][NH];
};

template <int MODEG>   // 1: gumbel from precomputed G; 0: inline threefry+logf
__global__ __launch_bounds__(512, 4)
void decode_1b(const float* __restrict__ cv,
               const float* __restrict__ mask_in,
               const float* __restrict__ Wref,
               const float* __restrict__ vvec,
               const double* __restrict__ qqbase,
               const float* __restrict__ M1T,
               const float* __restrict__ qq0,
               const double* __restrict__ A2,
               const float* __restrict__ G,
               float* __restrict__ out) {
  const int b = blockIdx.x;
  const int t = threadIdx.x;
  const int b256 = b << 8;
  const int w = t >> 6, l = t & 63;
  const int i = (w << 5) | (l >> 1);     // list position (pair of adjacent lanes)
  const int hHalf = l & 1;
  const int hb = hHalf << 6;
  const int h0 = l << 1;                 // this lane's qq-write pair
  const float LOG2E = 1.4426950408889634f;

  __shared__ union { PreSh pre; MainSh1 m; } sh;
  __shared__ short rowId0[NS];
  __shared__ int tmp8[4], nActSh0;

  // ---------- build initial active-row list ----------
  bool act0 = false; int preCnt = 0;
  if (t < NS) {
    act0 = !((t == 0) || (mask_in[(size_t)b256 + t] > 0.0f));
    uint64_t mb = __ballot(act0);
    int lane = t & 63, wv = t >> 6;
    preCnt = __popcll(mb & (((uint64_t)1 << lane) - 1));
    if (lane == 0) tmp8[wv] = (int)__popcll(mb);
  }
  __syncthreads();
  if (t < NS && act0) {
    int base = 0;
    for (int k = 0; k < (t >> 6); ++k) base += tmp8[k];
    rowId0[base + preCnt] = (short)t;
  }
  if (t == 0) nActSh0 = tmp8[0] + tmp8[1] + tmp8[2] + tmp8[3];
  __syncthreads();
  const int nAct0 = nActSh0;

  // ---------- Phase 1: refr = ref[myRow0][hb..hb+64) (bit-identical chunking) ----------
  int myRow = (i < nAct0) ? (int)rowId0[i] : 0;
  float refr[64];
#pragma unroll
  for (int j = 0; j < 64; ++j) refr[j] = 0.0f;

  for (int ec = 0; ec < 4; ++ec) {
    __syncthreads();
    for (int ii = t; ii < 32 * NH; ii += 512) {
      int r = ii >> 7, c = ii & 127;
      sh.pre.wS[r][c] = Wref[(ec * 32 + r) * NH + c];
    }
    for (int ii = t; ii < NS * 32; ii += 512) {
      int r = ii >> 5, c = ii & 31;
      sh.pre.cvS[r][c] = cv[((size_t)b256 + r) * NE + ec * 32 + c];
    }
    __syncthreads();
    for (int hc = 0; hc < 8; ++hc) {
      double a[8] = {0,0,0,0,0,0,0,0};
      for (int e = 0; e < 32; ++e) {
        double cd = (double)sh.pre.cvS[myRow][e];
        const float* wp = &sh.pre.wS[e][hb + hc * 8];
#pragma unroll
        for (int j = 0; j < 8; ++j) a[j] += cd * (double)wp[j];
      }
#pragma unroll
      for (int j = 0; j < 8; ++j) refr[hc * 8 + j] += (float)a[j];
    }
  }
  __syncthreads();  // pre dead, m live

  // ---------- prologue ----------
  if (!MODEG && t < NSTEPS) {
    uint32_t o0, o1;
    tf2x32(0u, 42u, 0u, (uint32_t)t, o0, o1);
    sh.m.keyL[t] = make_uint2(o0, o1);
  }
  if (t < NH) {
    sh.m.vvf[t] = vvec[t];
    sh.m.qq[t] = qq0[(size_t)b * NH + t];
  }
  __syncthreads();

  float g = 0.0f;
  if (i < nAct0) {
    if (MODEG) g = G[((size_t)b * NSTEPS + 0) * NS + myRow];
    else       g = gumbel_of(sh.m.keyL[0], (uint32_t)(b256 + myRow));
  }
  bool adoptNext = false;

  // ---------- 255 decode steps, ONE barrier each (two at step 0) ----------
  for (int step = 0; step < NSTEPS; ++step) {
    const int par = step & 1;
    const int nA = nAct0 - step;
    const bool active = (i < nA);

    // consume adoption decided last step
    if (adoptNext) {
      myRow = sh.m.sRowId[par ^ 1];
      const float4* rs4 = (const float4*)(&sh.m.refScr[par ^ 1][hb]);
#pragma unroll
      for (int q = 0; q < 16; ++q) {
        float4 v4 = rs4[q];
        refr[4 * q + 0] = v4.x; refr[4 * q + 1] = v4.y;
        refr[4 * q + 2] = v4.z; refr[4 * q + 3] = v4.w;
      }
      adoptNext = false;
    }
    // donor (always position nA-1) hands off unconditionally, pre-barrier
    if (active && i == nA - 1) {
      float4* rs4 = (float4*)(&sh.m.refScr[par][hb]);
#pragma unroll
      for (int q = 0; q < 16; ++q)
        rs4[q] = make_float4(refr[4 * q + 0], refr[4 * q + 1],
                             refr[4 * q + 2], refr[4 * q + 3]);
      sh.m.sRowId[par] = myRow;
    }

    // tanh partial over this thread's 64-wide h-slice
    double accH = 0.0;
    if (active) {
      double a0 = 0, a1 = 0, a2 = 0, a3 = 0;
      const float4* qq4 = (const float4*)(sh.m.qq + hb);
      const float4* vv4 = (const float4*)(sh.m.vvf + hb);
#pragma unroll
      for (int q = 0; q < 16; ++q) {
        float4 qv = qq4[q];
        float4 wv = vv4[q];
        a0 += (double)nr_tanh(qv.x + refr[4 * q + 0]) * (double)wv.x;
        a1 += (double)nr_tanh(qv.y + refr[4 * q + 1]) * (double)wv.y;
        a2 += (double)nr_tanh(qv.z + refr[4 * q + 2]) * (double)wv.z;
        a3 += (double)nr_tanh(qv.w + refr[4 * q + 3]) * (double)wv.w;
      }
      accH = (a0 + a1) + (a2 + a3);
    }
    double other = __shfl_xor(accH, 1, 64);
    float val = SENT_NEG; int bR = 0x7fffffff; float term = 0.0f; float lg = 0.0f;
    if (active) {
      double tot = hHalf ? (other + accH) : (accH + other);   // low + high
      float u_ = (float)tot;
      float logit = 10.0f * (float)tanh((double)u_);
      lg = logit;
      if (!hHalf) term = __builtin_amdgcn_exp2f(logit * LOG2E);  // lse term once/row
      val = logit + g;
      bR = myRow;
    }

    // wave reduce: payload (val, row, sum-term, logit)
    float bvv = val; float bss = term; float bL = lg;
#pragma unroll
    for (int mm = 1; mm <= 32; mm <<= 1) {
      float ov = __shfl_xor(bvv, mm, 64);
      int   oR = __shfl_xor(bR,  mm, 64);
      float os = __shfl_xor(bss, mm, 64);
      float oL = __shfl_xor(bL,  mm, 64);
      bss += os;
      if (ov > bvv || (ov == bvv && oR < bR)) { bvv = ov; bR = oR; bL = oL; }
    }
    if (l == 0) {
      sh.m.redV[par][w] = bvv; sh.m.redI[par][w] = bR;
      sh.m.redS[par][w] = bss; sh.m.redL[par][w] = bL;
    }
    __syncthreads();  // THE barrier (LDS-only drain)

    // final reduce: lanes 0-7 of every wave, 3-level butterfly, broadcast
    float rv = SENT_NEG2; int ri = 0x7fffffff; float rs = 0.0f; float rl = 0.0f;
    if (l < 8) {
      rv = sh.m.redV[par][l]; ri = sh.m.redI[par][l];
      rs = sh.m.redS[par][l]; rl = sh.m.redL[par][l];
    }
#pragma unroll
    for (int mm = 1; mm <= 4; mm <<= 1) {
      float ov = __shfl_xor(rv, mm, 64);
      int   oR = __shfl_xor(ri, mm, 64);
      float os = __shfl_xor(rs, mm, 64);
      float oL = __shfl_xor(rl, mm, 64);
      rs += os;
      if (ov > rv || (ov == rv && oR < ri)) { rv = ov; ri = oR; rl = oL; }
    }
    int BI = __shfl(ri, 0, 64);
    if ((unsigned)BI > 255u) BI = 0;

    const bool waveNext = ((w << 5) < nA - 1) && (step + 1 < NSTEPS);

    // EARLY A2 issue (post-barrier): latency overlaps out-write/gumbel/bookkeeping
    double a0v = 0.0, a1v = 0.0;
    if (step > 0 && waveNext) {
      const double* ap = A2 + (size_t)(b256 + BI) * NH + h0;
      a0v = ap[0]; a1v = ap[1];
    }

    if (t == 0) {
      float lp = rl - (float)log((double)rs);
      out[(size_t)b * NSTEPS + step] = (float)BI;
      out[(size_t)NBATCH * NSTEPS + (size_t)b * NSTEPS + step] = lp;
    }

    // register-resident compaction: adopter = pair whose row was selected
    adoptNext = active && (myRow == BI) && (i != nA - 1);

    // next-step gumbel
    if (step + 1 < NSTEPS && i < nA - 1) {
      int ridN = adoptNext ? sh.m.sRowId[par] : myRow;
      if (MODEG) g = G[((size_t)b * NSTEPS + (step + 1)) * NS + ridN];
      else       g = gumbel_of(sh.m.keyL[step + 1], (uint32_t)(b256 + ridN));
    }

    // ---- qq for next step: every needed wave writes the FULL row itself ----
    if (step == 0) {
      if (NSTEPS > 1) {
        const int hq = t >> 2, kq = t & 3;
        const float4* hrow = (const float4*)(cv + (size_t)(b256 + BI) * NE + kq * 32);
        const float4* m1p  = (const float4*)(M1T + (size_t)hq * NE + kq * 32);
        double am = dot32(hrow, m1p);
        am += __shfl_xor(am, 1, 64);
        am += __shfl_xor(am, 2, 64);
        if (kq == 0)
          sh.m.base128[hq] = qqbase[(size_t)b * NH + hq] + am;
        __syncthreads();  // step-0 only: base128 ready
        if (waveNext) {
          double b0 = A2[(size_t)(b256 + BI) * NH + h0];
          double b1 = A2[(size_t)(b256 + BI) * NH + h0 + 1];
          sh.m.qq[h0]     = (float)(sh.m.base128[h0]     + b0);
          sh.m.qq[h0 + 1] = (float)(sh.m.base128[h0 + 1] + b1);
        }
      }
    } else if (waveNext) {
      sh.m.qq[h0]     = (float)(sh.m.base128[h0]     + a0v);
      sh.m.qq[h0 + 1] = (float)(sh.m.base128[h0 + 1] + a1v);
    }
    // no trailing barrier: each wave reads only its own qq writes next step
  }
}

// ======================= round-2 passing kernel (no-ws fallback, unchanged) ==========
__device__ __forceinline__ float fast_tanh_ref(float x) {
  const float Chi = 2.8853900432586670f;
  const float Clo = 3.8519259822379735e-08f;
  float m = fmaf(x, Chi, x * Clo);
  float tt = exp2f(m);
  return 1.0f - 2.0f / (tt + 1.0f);
}

struct MainShR {
  float  query[NE];
  float  qq[NH];
  float  hbar[NE];
  float  inith[NE];
  float  hcur[NE];
  alignas(16) double vvd[NH];
  float  logitArr[NS];
  float  maskArr[NS];
  uint2  keyL[NSTEPS];
  float  meanv[NE];
  float  redV[4];
  int    redI[4];
  double redS[4];
  int    idxSh;
};
struct PreShR {
  float cvS[NS][33];
  float wS[32][NH];
};

__global__ __launch_bounds__(256, 2)
void decoder_kernel_ref(const float* __restrict__ cv, const float* __restrict__ mask_in,
                        const float* __restrict__ liw, const float* __restrict__ Wc,
                        const float* __restrict__ bc, const float* __restrict__ Wv,
                        const float* __restrict__ bv, const float* __restrict__ Wq,
                        const float* __restrict__ Wref, const float* __restrict__ vvec,
                        float* __restrict__ out) {
  const int b = blockIdx.x;
  const int t = threadIdx.x;
  const int b256 = b << 8;
  __shared__ union { PreShR pre; MainShR m; } sh;

  float refr[NH];
#pragma unroll
  for (int h = 0; h < NH; ++h) refr[h] = 0.0f;
  for (int ec = 0; ec < 4; ++ec) {
    const int e0 = ec * 32;
    __syncthreads();
    for (int i = t; i < 32 * NH; i += 256) {
      int r = i >> 7, h = i & 127;
      sh.pre.wS[r][h] = Wref[(e0 + r) * NH + h];
    }
    for (int i = t; i < NS * 32; i += 256) {
      int s2 = i >> 5, j = i & 31;
      sh.pre.cvS[s2][j] = cv[((size_t)b256 + s2) * NE + e0 + j];
    }
    __syncthreads();
#pragma unroll
    for (int hc = 0; hc < 16; ++hc) {
      double a[8] = {0,0,0,0,0,0,0,0};
      for (int e = 0; e < 32; ++e) {
        double cd = (double)sh.pre.cvS[t][e];
#pragma unroll
        for (int j = 0; j < 8; ++j) a[j] += cd * (double)sh.pre.wS[e][hc * 8 + j];
      }
#pragma unroll
      for (int j = 0; j < 8; ++j) refr[hc * 8 + j] += (float)a[j];
    }
  }
  __syncthreads();

  if (t < NSTEPS) {
    uint32_t o0, o1;
    tf2x32(0u, 42u, 0u, (uint32_t)t, o0, o1);
    sh.m.keyL[t] = make_uint2(o0, o1);
  }
  if (t < NH) sh.m.vvd[t] = (double)vvec[t];
  sh.m.maskArr[t] = (mask_in[(size_t)b256 + t] > 0.0f || t == 0) ? 1.0f : 0.0f;
  if (t < NE) {
    double s64 = 0.0;
    for (int s2 = 0; s2 < NS; ++s2) s64 += (double)cv[((size_t)b256 + s2) * NE + t];
    sh.m.meanv[t] = (float)(s64 * (1.0 / 256.0));
  }
  __syncthreads();
  if (t < NE) {
    double acc = 0.0;
    for (int e = 0; e < NE; ++e) acc += (double)sh.m.meanv[e] * (double)Wc[e * NE + t];
    float hbv = (float)acc + bc[t];
    sh.m.hbar[t] = hbv;
    double acc2 = 0.0;
    for (int k = 0; k < 2 * NE; ++k) acc2 += (double)liw[k] * (double)Wv[k * NE + t];
    float r0 = (float)acc2 + bv[t];
    sh.m.query[t] = hbv + r0;
  }
  __syncthreads();

  for (int step = 0; step < NSTEPS; ++step) {
    if (t < NH) {
      double acc = 0.0;
      for (int k = 0; k < NE; ++k) acc += (double)sh.m.query[k] * (double)Wq[k * NH + t];
      sh.m.qq[t] = (float)acc;
    }
    __syncthreads();

    float logit;
    bool masked = (sh.m.maskArr[t] != 0.0f);
    if (!masked) {
      double a0 = 0.0, a1 = 0.0, a2 = 0.0, a3 = 0.0;
      const float4*  qq4 = (const float4*)sh.m.qq;
      const double2* vv2 = (const double2*)sh.m.vvd;
#pragma unroll
      for (int h4 = 0; h4 < 32; ++h4) {
        float4  q  = qq4[h4];
        double2 va = vv2[2 * h4];
        double2 vb = vv2[2 * h4 + 1];
        a0 += (double)fast_tanh_ref(q.x + refr[4 * h4 + 0]) * va.x;
        a1 += (double)fast_tanh_ref(q.y + refr[4 * h4 + 1]) * va.y;
        a2 += (double)fast_tanh_ref(q.z + refr[4 * h4 + 2]) * vb.x;
        a3 += (double)fast_tanh_ref(q.w + refr[4 * h4 + 3]) * vb.y;
      }
      float u_ = (float)((a0 + a1) + (a2 + a3));
      logit = 10.0f * (float)tanh((double)u_);
    } else {
      logit = NEGINF;
    }
    sh.m.logitArr[t] = logit;

    uint2 key = sh.m.keyL[step];
    uint32_t j = (uint32_t)(b256 + t);
    uint32_t o0, o1;
    tf2x32(key.x, key.y, 0u, j, o0, o1);
    uint32_t bits = o0 ^ o1;
    float f = __uint_as_float((bits >> 9) | 0x3f800000u) - 1.0f;
    float u = (f == 0.0f) ? 1.17549435e-38f : f;
    float l1 = (float)(-log((double)u));
    float g  = (float)(-log((double)l1));
    float val = logit + g;
    double term = exp((double)logit);

    float bv_ = val; int bi = t; double bs = term;
#pragma unroll
    for (int m = 1; m <= 32; m <<= 1) {
      float  ov = __shfl_xor(bv_, m, 64);
      int    oi = __shfl_xor(bi,  m, 64);
      double os = __shfl_xor(bs,  m, 64);
      if (ov > bv_ || (ov == bv_ && oi < bi)) { bv_ = ov; bi = oi; }
      bs += os;
    }
    int w = t >> 6;
    if ((t & 63) == 0) { sh.m.redV[w] = bv_; sh.m.redI[w] = bi; sh.m.redS[w] = bs; }
    __syncthreads();

    if (t == 0) {
      float BV = sh.m.redV[0]; int BI = sh.m.redI[0];
      for (int k = 1; k < 4; ++k) {
        float ov = sh.m.redV[k]; int oi = sh.m.redI[k];
        if (ov > BV || (ov == BV && oi < BI)) { BV = ov; BI = oi; }
      }
      double SS = ((sh.m.redS[0] + sh.m.redS[1]) + (sh.m.redS[2] + sh.m.redS[3]));
      sh.m.idxSh = BI;
      float lp = sh.m.logitArr[BI] - (float)log(SS);
      out[(size_t)b * NSTEPS + step] = (float)BI;
      out[(size_t)NBATCH * NSTEPS + (size_t)b * NSTEPS + step] = lp;
    }
    __syncthreads();

    int idx = sh.m.idxSh;
    if (t == idx) sh.m.maskArr[t] = 1.0f;
    if (t < NE) {
      float hc = cv[((size_t)b256 + idx) * NE + t];
      sh.m.hcur[t] = hc;
      if (step == 0) sh.m.inith[t] = hc;
    }
    __syncthreads();

    if (t < NE) {
      double acc2 = 0.0;
      for (int k = 0; k < NE; ++k) acc2 += (double)sh.m.inith[k] * (double)Wv[k * NE + t];
      for (int k = 0; k < NE; ++k) acc2 += (double)sh.m.hcur[k] * (double)Wv[(NE + k) * NE + t];
      float mm = (float)acc2 + bv[t];
      sh.m.query[t] = sh.m.hbar[t] + mm;
    }
    __syncthreads();
  }
}

extern "C" void kernel_launch(void* const* d_in, const int* in_sizes, int n_in,
                              void* d_out, int out_size, void* d_ws, size_t ws_size,
                              hipStream_t stream) {
  const float* cv   = (const float*)d_in[0];
  const float* mask = (const float*)d_in[2];
  const float* liw  = (const float*)d_in[3];
  const float* Wc   = (const float*)d_in[4];
  const float* bc   = (const float*)d_in[5];
  const float* Wv   = (const float*)d_in[6];
  const float* bv   = (const float*)d_in[7];
  const float* Wq   = (const float*)d_in[8];
  const float* Wref = (const float*)d_in[9];
  const float* vv   = (const float*)d_in[10];
  (void)in_sizes; (void)n_in; (void)out_size;

  const size_t SZ_QQB = (size_t)NBATCH * NH * sizeof(double);      // 512 KB
  const size_t SZ_M   = (size_t)NE * NH * sizeof(float);           // 64 KB each
  const size_t SZ_QQ0 = (size_t)NBATCH * NH * sizeof(float);       // 256 KB
  const size_t SZ_A2  = (size_t)NBATCH * NS * NH * sizeof(double); // 134 MB
  const size_t SZ_G   = (size_t)NBATCH * NSTEPS * NS * sizeof(float); // 133.6 MB
  const size_t need_pre = SZ_QQB + 2 * SZ_M + SZ_QQ0 + 512 + SZ_A2;
  const size_t need_g   = need_pre + SZ_G;

  if (ws_size >= need_pre) {
    char* p = (char*)d_ws;
    double* qqbase = (double*)p;            p += SZ_QQB;
    float*  M1T    = (float*)p;             p += SZ_M;
    float*  M2T    = (float*)p;             p += SZ_M;
    float*  qq0    = (float*)p;             p += SZ_QQ0;
    float*  rest0  = (float*)p;             p += 512;
    double* A2     = (double*)p;            p += SZ_A2;
    float*  G      = (float*)p;

    k1_mats<<<257, 128, 0, stream>>>(Wv, Wq, liw, bv, M1T, M2T, rest0);
    k2_base<<<NBATCH, 128, 0, stream>>>(cv, Wc, bc, bv, Wq, rest0, qqbase, qq0);
    k_a2v3<<<NBATCH * 8, 256, 0, stream>>>(cv, M2T, A2);
    if (ws_size >= need_g) {
      k_gum<<<dim3(NBATCH, NSTEPS), 256, 0, stream>>>(G);
      decode_1b<1><<<NBATCH, 512, 0, stream>>>(cv, mask, Wref, vv, qqbase, M1T,
                                               qq0, A2, G, (float*)d_out);
    } else {
      decode_1b<0><<<NBATCH, 512, 0, stream>>>(cv, mask, Wref, vv, qqbase, M1T,
                                               qq0, A2, nullptr, (float*)d_out);
    }
  } else {
    decoder_kernel_ref<<<NBATCH, 256, 0, stream>>>(cv, mask, liw, Wc, bc, Wv, bv,
                                                   Wq, Wref, vv, (float*)d_out);
  }
}